// Round 16
// baseline (108.874 us; speedup 1.0000x reference)
//
#include <hip/hip_runtime.h>
#include <stdint.h>

// ============================ problem dims ============================
// hidden_states [4,2048,2048] f32, rows R=8192, H=2048, BD=N=VBD=256, top-8
// out = primary + sigmoid(top1) * gelu_lowrank(softmax_top8 @ gathered vals)
// Key restructure: down-proj linear -> PV = slot_values @ Wd^T precomputed.
// R15 lesson: k_out plateaus at 46-48us across occupancy 21-47% and 7
// structural variants.  R16 experiment: SPLIT k_out into k_aux (GEMM ->
// bf16 aux, gate folded) + k_add (pure streaming out = primary + aux) to
// discriminate stream-throttled-by-GEMM vs intrinsic-BW-plateau.

typedef float f32x4 __attribute__((ext_vector_type(4)));
typedef unsigned short u16x8 __attribute__((ext_vector_type(8)));
typedef unsigned short u16x4 __attribute__((ext_vector_type(4)));
typedef __bf16 bf16x8 __attribute__((ext_vector_type(8)));

// ============================ ws layout (bytes) ============================
#define WS_QW    0u          // u16 [256*2048]  q_proj_w bf16
#define WS_SK    1048576u    // u16 [256*256]   slot_keys bf16
#define WS_SV    1179648u    // u16 [256*2048]  slot_values bf16
#define WS_VDW   2228224u    // u16 [256*2048]  value_down_w bf16
#define WS_VUP   3276800u    // u16 [2048*256]  value_up_w bf16
#define WS_REL   4325376u    // f32 [256]       log(reliability)
#define WS_PV    4326400u    // f32 [256*256]   slot_values @ Wd^T
#define WS_GATE  4588544u    // f32 [8192]      sigmoid(top1)
#define WS_QP    4621312u    // f32 [2][8192][256] query split-K partials
#define WS_D     21398528u   // u16 [8192*256]  gelu(down) bf16
#define WS_AUX   25592832u   // u16 [8192*2048] gate*(D@vup^T) bf16 (32 MB)
#define WS_NEED_SPLIT 59147264u   // ws bytes needed for the split path

static __device__ __forceinline__ unsigned short f2bf(float f) {
  union { float f; unsigned int u; } v; v.f = f;
  unsigned int r = v.u + 0x7FFFu + ((v.u >> 16) & 1u);
  return (unsigned short)(r >> 16);
}
static __device__ __forceinline__ float bf2f(unsigned short b) {
  union { unsigned int u; float f; } v; v.u = ((unsigned int)b) << 16;
  return v.f;
}
static __device__ __forceinline__ bf16x8 as_bf16(u16x8 v) {
  return __builtin_bit_cast(bf16x8, v);
}
static __device__ __forceinline__ float gelu_tanh(float x) {
  float u = 0.7978845608028654f * (x + 0.044715f * x * x * x);
  return 0.5f * x * (1.0f + tanhf(u));
}

// ============================ K0: convert weights ============================
__global__ void k_prep(const float* __restrict__ qw, const float* __restrict__ sk,
                       const float* __restrict__ sv, const float* __restrict__ vdw,
                       const float* __restrict__ vup, const float* __restrict__ rel,
                       unsigned char* __restrict__ ws) {
  unsigned short* o_qw  = (unsigned short*)(ws + WS_QW);
  unsigned short* o_sk  = (unsigned short*)(ws + WS_SK);
  unsigned short* o_sv  = (unsigned short*)(ws + WS_SV);
  unsigned short* o_vdw = (unsigned short*)(ws + WS_VDW);
  unsigned short* o_vup = (unsigned short*)(ws + WS_VUP);
  float* o_rel = (float*)(ws + WS_REL);
  int tid = blockIdx.x * blockDim.x + threadIdx.x;
  int stride = gridDim.x * blockDim.x;
  for (int g = tid; g < 540736; g += stride) {
    const float* src; unsigned short* dst; int i;
    if      (g < 131072) { src = qw;  dst = o_qw;  i = g; }
    else if (g < 147456) { src = sk;  dst = o_sk;  i = g - 131072; }
    else if (g < 278528) { src = sv;  dst = o_sv;  i = g - 147456; }
    else if (g < 409600) { src = vdw; dst = o_vdw; i = g - 278528; }
    else if (g < 540672) { src = vup; dst = o_vup; i = g - 409600; }
    else {
      int i4 = (g - 540672) * 4;
      #pragma unroll
      for (int j = 0; j < 4; j++) o_rel[i4 + j] = logf(fmaxf(rel[i4 + j], 1e-10f));
      continue;
    }
    f32x4 v = *(const f32x4*)(src + (size_t)i * 4);
    u16x4 o;
    #pragma unroll
    for (int j = 0; j < 4; j++) o[j] = f2bf(v[j]);
    *(u16x4*)(dst + (size_t)i * 4) = o;
  }
}

// ============================ K_PV: PV = sv @ vdw^T (barrier-free K) ============================
__global__ __launch_bounds__(256, 4) void k_pv(unsigned char* __restrict__ ws) {
  const unsigned short* sv  = (const unsigned short*)(ws + WS_SV);
  const unsigned short* vdw = (const unsigned short*)(ws + WS_VDW);
  float* PV = (float*)(ws + WS_PV);
  __shared__ float red[4][16][16];
  int t = threadIdx.x, lane = t & 63, w = t >> 6;
  int nt = blockIdx.x >> 4, vt = blockIdx.x & 15;
  const unsigned short* aLane = sv  + (size_t)(nt * 16 + (lane & 15)) * 2048 + (lane >> 4) * 8 + w * 512;
  const unsigned short* bLane = vdw + (size_t)(vt * 16 + (lane & 15)) * 2048 + (lane >> 4) * 8 + w * 512;
  f32x4 acc = {0.f, 0.f, 0.f, 0.f};
  #pragma unroll
  for (int kt = 0; kt < 16; kt++) {
    bf16x8 a = as_bf16(*(const u16x8*)(aLane + kt * 32));
    bf16x8 b = as_bf16(*(const u16x8*)(bLane + kt * 32));
    acc = __builtin_amdgcn_mfma_f32_16x16x32_bf16(a, b, acc, 0, 0, 0);
  }
  int col = lane & 15, row0 = (lane >> 4) * 4;
  #pragma unroll
  for (int j = 0; j < 4; j++) red[w][row0 + j][col] = acc[j];
  __syncthreads();
  if (w == 0) {
    #pragma unroll
    for (int i = 0; i < 4; i++) {
      int idx = i * 64 + lane, r = idx >> 4, c = idx & 15;
      float s = red[0][r][c] + red[1][r][c] + red[2][r][c] + red[3][r][c];
      PV[(nt * 16 + r) * 256 + vt * 16 + c] = s;
    }
  }
}

// ============================ K1: query GEMM (split-K=2, pipelined) ============================
__global__ __launch_bounds__(256, 4) void k_query(const float* __restrict__ hs,
                                                  unsigned char* __restrict__ ws) {
  const unsigned short* qw = (const unsigned short*)(ws + WS_QW);
  float* qp = (float*)(ws + WS_QP);
  __shared__ __align__(16) unsigned short As[32 * 64];    // 4 KB
  __shared__ __align__(16) unsigned short Bs[256 * 64];   // 32 KB
  int t = threadIdx.x, lane = t & 63, w = t >> 6;
  int rt = blockIdx.x >> 1, ks = blockIdx.x & 1;
  int row0 = rt * 32, kbase = ks * 1024;
  f32x4 acc[2][4] = {};
  int sr = t >> 3, sc = t & 7;
  const float* aptr = hs + (size_t)(row0 + sr) * 2048 + kbase + sc * 8;
  const unsigned short* bptr = qw + (size_t)sr * 2048 + kbase + sc * 8;
  f32x4 pa0, pa1;
  u16x8 pb0, pb1, pb2, pb3, pb4, pb5, pb6, pb7;
  pa0 = *(const f32x4*)(aptr);
  pa1 = *(const f32x4*)(aptr + 4);
  pb0 = *(const u16x8*)(bptr + (size_t)0 * 32 * 2048);
  pb1 = *(const u16x8*)(bptr + (size_t)1 * 32 * 2048);
  pb2 = *(const u16x8*)(bptr + (size_t)2 * 32 * 2048);
  pb3 = *(const u16x8*)(bptr + (size_t)3 * 32 * 2048);
  pb4 = *(const u16x8*)(bptr + (size_t)4 * 32 * 2048);
  pb5 = *(const u16x8*)(bptr + (size_t)5 * 32 * 2048);
  pb6 = *(const u16x8*)(bptr + (size_t)6 * 32 * 2048);
  pb7 = *(const u16x8*)(bptr + (size_t)7 * 32 * 2048);
  for (int kt = 0; kt < 16; kt++) {
    __syncthreads();
    {
      u16x8 o;
      #pragma unroll
      for (int j = 0; j < 4; j++) { o[j] = f2bf(pa0[j]); o[4 + j] = f2bf(pa1[j]); }
      *(u16x8*)&As[sr * 64 + ((sc ^ (sr & 7)) * 8)] = o;
      u16x8 pb[8] = {pb0, pb1, pb2, pb3, pb4, pb5, pb6, pb7};
      #pragma unroll
      for (int i = 0; i < 8; i++) {
        int n = i * 32 + sr;
        *(u16x8*)&Bs[n * 64 + ((sc ^ (n & 7)) * 8)] = pb[i];
      }
    }
    __syncthreads();
    if (kt < 15) {
      int off = (kt + 1) * 64;
      pa0 = *(const f32x4*)(aptr + off);
      pa1 = *(const f32x4*)(aptr + off + 4);
      pb0 = *(const u16x8*)(bptr + (size_t)0 * 32 * 2048 + off);
      pb1 = *(const u16x8*)(bptr + (size_t)1 * 32 * 2048 + off);
      pb2 = *(const u16x8*)(bptr + (size_t)2 * 32 * 2048 + off);
      pb3 = *(const u16x8*)(bptr + (size_t)3 * 32 * 2048 + off);
      pb4 = *(const u16x8*)(bptr + (size_t)4 * 32 * 2048 + off);
      pb5 = *(const u16x8*)(bptr + (size_t)5 * 32 * 2048 + off);
      pb6 = *(const u16x8*)(bptr + (size_t)6 * 32 * 2048 + off);
      pb7 = *(const u16x8*)(bptr + (size_t)7 * 32 * 2048 + off);
    }
    #pragma unroll
    for (int kk = 0; kk < 2; kk++) {
      int ck = kk * 4 + (lane >> 4);
      bf16x8 a[2], b[4];
      #pragma unroll
      for (int mf = 0; mf < 2; mf++) {
        int arow = mf * 16 + (lane & 15);
        a[mf] = as_bf16(*(const u16x8*)&As[arow * 64 + ((ck ^ (arow & 7)) * 8)]);
      }
      #pragma unroll
      for (int nf = 0; nf < 4; nf++) {
        int brow = w * 64 + nf * 16 + (lane & 15);
        b[nf] = as_bf16(*(const u16x8*)&Bs[brow * 64 + ((ck ^ (brow & 7)) * 8)]);
      }
      #pragma unroll
      for (int mf = 0; mf < 2; mf++)
        #pragma unroll
        for (int nf = 0; nf < 4; nf++)
          acc[mf][nf] = __builtin_amdgcn_mfma_f32_16x16x32_bf16(a[mf], b[nf], acc[mf][nf], 0, 0, 0);
    }
  }
  float* outp = qp + (size_t)ks * 8192 * 256;
  #pragma unroll
  for (int mf = 0; mf < 2; mf++) {
    int row = row0 + mf * 16 + (lane >> 4) * 4;
    #pragma unroll
    for (int nf = 0; nf < 4; nf++) {
      int col = w * 64 + nf * 16 + (lane & 15);
      #pragma unroll
      for (int j = 0; j < 4; j++) outp[(size_t)(row + j) * 256 + col] = acc[mf][nf][j];
    }
  }
}

// ============================ K2: scores + wave-parallel top8 + PV gather ============================
#define QSTR 264   // ushort stride
#define SSTR 260   // f32 stride
__global__ __launch_bounds__(256, 4) void k_score(unsigned char* __restrict__ ws) {
  const float* qp = (const float*)(ws + WS_QP);
  const unsigned short* sk = (const unsigned short*)(ws + WS_SK);
  const float* relm = (const float*)(ws + WS_REL);
  const float* PV = (const float*)(ws + WS_PV);
  float* gates = (float*)(ws + WS_GATE);
  unsigned short* D = (unsigned short*)(ws + WS_D);
  __shared__ __align__(16) unsigned short Qs[16 * QSTR];
  __shared__ __align__(16) float Ss[16 * SSTR];
  int t = threadIdx.x, lane = t & 63, w = t >> 6;
  int row0 = blockIdx.x * 16;
  #pragma unroll
  for (int i = 0; i < 4; i++) {
    int id = i * 256 + t, r = id >> 6, c4 = id & 63;
    const float* p0 = qp + (size_t)(row0 + r) * 256 + c4 * 4;
    f32x4 a = *(const f32x4*)p0;
    f32x4 b = *(const f32x4*)(p0 + 8192 * 256);
    u16x4 o;
    #pragma unroll
    for (int j = 0; j < 4; j++) o[j] = f2bf(a[j] + b[j]);
    *(u16x4*)&Qs[r * QSTR + c4 * 4] = o;
  }
  __syncthreads();
  {
    f32x4 acc[4] = {};
    for (int ksb = 0; ksb < 8; ksb++) {
      int ck = lane >> 4;
      bf16x8 a = as_bf16(*(const u16x8*)&Qs[(lane & 15) * QSTR + ksb * 32 + ck * 8]);
      #pragma unroll
      for (int nf = 0; nf < 4; nf++) {
        int n = w * 64 + nf * 16 + (lane & 15);
        bf16x8 b = as_bf16(*(const u16x8*)&sk[(size_t)n * 256 + ksb * 32 + ck * 8]);
        acc[nf] = __builtin_amdgcn_mfma_f32_16x16x32_bf16(a, b, acc[nf], 0, 0, 0);
      }
    }
    #pragma unroll
    for (int nf = 0; nf < 4; nf++) {
      int n = w * 64 + nf * 16 + (lane & 15);
      float rm = relm[n];
      int rr = (lane >> 4) * 4;
      #pragma unroll
      for (int j = 0; j < 4; j++) Ss[(rr + j) * SSTR + n] = acc[nf][j] * 0.0625f + rm;
    }
  }
  __syncthreads();
  for (int rr = 0; rr < 4; rr++) {
    int row = w * 4 + rr;
    f32x4 sv4 = *(const f32x4*)&Ss[row * SSTR + lane * 4];
    unsigned int key[4];
    #pragma unroll
    for (int j = 0; j < 4; j++) {
      unsigned int u = __builtin_bit_cast(unsigned int, sv4[j]);
      unsigned int os = (u & 0x80000000u) ? ~u : (u | 0x80000000u);
      key[j] = (os & 0xFFFFFF00u) | (unsigned int)(255 - (lane * 4 + j));
    }
    unsigned int win[8];
    #pragma unroll
    for (int e = 0; e < 8; e++) {
      unsigned int m01 = key[0] > key[1] ? key[0] : key[1];
      unsigned int m23 = key[2] > key[3] ? key[2] : key[3];
      unsigned int m = m01 > m23 ? m01 : m23;
      #pragma unroll
      for (int d = 1; d < 64; d <<= 1) {
        unsigned int o = (unsigned int)__shfl_xor((int)m, d, 64);
        m = o > m ? o : m;
      }
      win[e] = m;
      #pragma unroll
      for (int j = 0; j < 4; j++) if (key[j] == m) key[j] = 0u;
    }
    float s8[8]; int i8[8];
    #pragma unroll
    for (int e = 0; e < 8; e++) {
      i8[e] = 255 - (int)(win[e] & 0xFFu);
      unsigned int os = win[e] & 0xFFFFFF00u;
      unsigned int u = (os & 0x80000000u) ? (os ^ 0x80000000u) : ~os;
      s8[e] = __builtin_bit_cast(float, u);
    }
    float m0 = s8[0], sum = 0.f, we[8];
    #pragma unroll
    for (int e = 0; e < 8; e++) { we[e] = expf(s8[e] - m0); sum += we[e]; }
    float inv = 1.f / sum;
    f32x4 accv = {0.f, 0.f, 0.f, 0.f};
    #pragma unroll
    for (int e = 0; e < 8; e++) {
      float wk = we[e] * inv;
      f32x4 p = *(const f32x4*)(PV + (size_t)i8[e] * 256 + lane * 4);
      #pragma unroll
      for (int j = 0; j < 4; j++) accv[j] += wk * p[j];
    }
    u16x4 o;
    #pragma unroll
    for (int j = 0; j < 4; j++) o[j] = f2bf(gelu_tanh(accv[j]));
    *(u16x4*)&D[(size_t)(row0 + row) * 256 + lane * 4] = o;
    if (lane == 0) gates[row0 + row] = 1.f / (1.f + expf(-m0));
  }
}

// ============================ K3a: aux GEMM (R13 k_out minus primary stream) ============================
// aux[r,h] = gate[r] * (D[r,:] @ vup[h,:]) -> bf16.  BM=64 x BN=128,
// 2048 blocks, (256,4), reg-prefetch K-pipeline, LDS-restage epilogue.
union KAuxLds {
  unsigned short AB[12288];        // As 64x64 at [0], Bs 128x64 at +4096
  float stage[32 * 132];
};
__global__ __launch_bounds__(256, 4) void k_aux(unsigned char* __restrict__ ws) {
  const unsigned short* D = (const unsigned short*)(ws + WS_D);
  const unsigned short* vup = (const unsigned short*)(ws + WS_VUP);
  const float* gates = (const float*)(ws + WS_GATE);
  unsigned short* aux = (unsigned short*)(ws + WS_AUX);
  __shared__ __align__(16) KAuxLds u;
  __shared__ float gate_s[64];
  unsigned short* As = u.AB;
  unsigned short* Bs = u.AB + 4096;
  int t = threadIdx.x, lane = t & 63, w = t >> 6;
  int bid = blockIdx.x;
  int L = (bid & 7) * 256 + (bid >> 3);
  int rt = L >> 4, ct = L & 15;
  int wm = w >> 1, wn = w & 1;
  int sr = t >> 3, sc = t & 7;
  const unsigned short* aptr = D + (size_t)(rt * 64 + sr) * 256 + sc * 8;
  const unsigned short* bptr = vup + (size_t)(ct * 128 + sr) * 256 + sc * 8;
  u16x8 pA0, pA1, pB0, pB1, pB2, pB3;
  pA0 = *(const u16x8*)(aptr);
  pA1 = *(const u16x8*)(aptr + 32 * 256);
  pB0 = *(const u16x8*)(bptr);
  pB1 = *(const u16x8*)(bptr + 32 * 256);
  pB2 = *(const u16x8*)(bptr + 64 * 256);
  pB3 = *(const u16x8*)(bptr + 96 * 256);
  if (t < 64) gate_s[t] = gates[rt * 64 + t];
  f32x4 acc[2][4] = {};
  for (int k0 = 0; k0 < 256; k0 += 64) {
    __syncthreads();
    {
      int r0 = sr, r1 = sr + 32, r2 = sr + 64, r3 = sr + 96;
      *(u16x8*)&As[r0 * 64 + ((sc ^ (r0 & 7)) * 8)] = pA0;
      *(u16x8*)&As[r1 * 64 + ((sc ^ (r1 & 7)) * 8)] = pA1;
      *(u16x8*)&Bs[r0 * 64 + ((sc ^ (r0 & 7)) * 8)] = pB0;
      *(u16x8*)&Bs[r1 * 64 + ((sc ^ (r1 & 7)) * 8)] = pB1;
      *(u16x8*)&Bs[r2 * 64 + ((sc ^ (r2 & 7)) * 8)] = pB2;
      *(u16x8*)&Bs[r3 * 64 + ((sc ^ (r3 & 7)) * 8)] = pB3;
    }
    __syncthreads();
    if (k0 < 192) {
      int off = k0 + 64;
      pA0 = *(const u16x8*)(aptr + off);
      pA1 = *(const u16x8*)(aptr + 32 * 256 + off);
      pB0 = *(const u16x8*)(bptr + off);
      pB1 = *(const u16x8*)(bptr + 32 * 256 + off);
      pB2 = *(const u16x8*)(bptr + 64 * 256 + off);
      pB3 = *(const u16x8*)(bptr + 96 * 256 + off);
    }
    #pragma unroll
    for (int kk = 0; kk < 2; kk++) {
      int ck = kk * 4 + (lane >> 4);
      bf16x8 a[2], b[4];
      #pragma unroll
      for (int mf = 0; mf < 2; mf++) {
        int ar = wm * 32 + mf * 16 + (lane & 15);
        a[mf] = as_bf16(*(const u16x8*)&As[ar * 64 + ((ck ^ (ar & 7)) * 8)]);
      }
      #pragma unroll
      for (int nf = 0; nf < 4; nf++) {
        int br = wn * 64 + nf * 16 + (lane & 15);
        b[nf] = as_bf16(*(const u16x8*)&Bs[br * 64 + ((ck ^ (br & 7)) * 8)]);
      }
      #pragma unroll
      for (int mf = 0; mf < 2; mf++)
        #pragma unroll
        for (int nf = 0; nf < 4; nf++)
          acc[mf][nf] = __builtin_amdgcn_mfma_f32_16x16x32_bf16(a[mf], b[nf], acc[mf][nf], 0, 0, 0);
    }
  }
  #pragma unroll
  for (int c = 0; c < 2; c++) {
    __syncthreads();
    if (wm == c) {
      #pragma unroll
      for (int mf = 0; mf < 2; mf++) {
        #pragma unroll
        for (int nf = 0; nf < 4; nf++) {
          int col = wn * 64 + nf * 16 + (lane & 15);
          #pragma unroll
          for (int j = 0; j < 4; j++) {
            int r = mf * 16 + (lane >> 4) * 4 + j;
            u.stage[r * 132 + col] = acc[mf][nf][j];
          }
        }
      }
    }
    __syncthreads();
    #pragma unroll
    for (int i = 0; i < 4; i++) {
      int idx = i * 256 + t, r = idx >> 5, c4 = idx & 31;
      int row = rt * 64 + c * 32 + r;
      float g = gate_s[c * 32 + r];
      f32x4 s = *(const f32x4*)&u.stage[r * 132 + c4 * 4];
      u16x4 o;
      #pragma unroll
      for (int j = 0; j < 4; j++) o[j] = f2bf(g * s[j]);
      *(u16x4*)&aux[(size_t)row * 2048 + ct * 128 + c4 * 4] = o;
    }
  }
}

// ============================ K3b: pure streaming add ============================
// out = primary + bf16(aux).  160 MB total; the direct BW-ceiling test.
__global__ __launch_bounds__(256, 8) void k_add(const float* __restrict__ primary,
                                                const unsigned short* __restrict__ aux,
                                                float* __restrict__ out) {
  int tid = blockIdx.x * 256 + threadIdx.x;
  #pragma unroll
  for (int i = 0; i < 8; i++) {
    size_t idx = (size_t)(tid + i * 524288) * 4;   // f32x4 granularity
    f32x4 p = *(const f32x4*)(primary + idx);
    u16x4 a = *(const u16x4*)(aux + idx);
    f32x4 o;
    #pragma unroll
    for (int j = 0; j < 4; j++) o[j] = p[j] + bf2f(a[j]);
    *(f32x4*)(out + idx) = o;
  }
}

// ============================ K3 fallback: fused up-GEMM + epilogue (R13 best) ============================
union KOutLds {
  unsigned short AB[12288];
  float stage[32 * 132];
};
__global__ __launch_bounds__(256, 4) void k_out(const float* __restrict__ primary,
                                                float* __restrict__ out,
                                                unsigned char* __restrict__ ws) {
  const unsigned short* D = (const unsigned short*)(ws + WS_D);
  const unsigned short* vup = (const unsigned short*)(ws + WS_VUP);
  const float* gates = (const float*)(ws + WS_GATE);
  __shared__ __align__(16) KOutLds u;
  __shared__ float gate_s[64];
  unsigned short* As = u.AB;
  unsigned short* Bs = u.AB + 4096;
  int t = threadIdx.x, lane = t & 63, w = t >> 6;
  int bid = blockIdx.x;
  int L = (bid & 7) * 256 + (bid >> 3);
  int rt = L >> 4, ct = L & 15;
  int wm = w >> 1, wn = w & 1;
  const float* pbase = primary + (size_t)(rt * 64 + (t >> 5)) * 2048 + ct * 128 + (t & 31) * 4;
  f32x4 pref[2][4];
  #pragma unroll
  for (int i = 0; i < 4; i++)
    pref[0][i] = *(const f32x4*)(pbase + (size_t)(i * 8) * 2048);
  int sr = t >> 3, sc = t & 7;
  const unsigned short* aptr = D + (size_t)(rt * 64 + sr) * 256 + sc * 8;
  const unsigned short* bptr = vup + (size_t)(ct * 128 + sr) * 256 + sc * 8;
  u16x8 pA0, pA1, pB0, pB1, pB2, pB3;
  pA0 = *(const u16x8*)(aptr);
  pA1 = *(const u16x8*)(aptr + 32 * 256);
  pB0 = *(const u16x8*)(bptr);
  pB1 = *(const u16x8*)(bptr + 32 * 256);
  pB2 = *(const u16x8*)(bptr + 64 * 256);
  pB3 = *(const u16x8*)(bptr + 96 * 256);
  if (t < 64) gate_s[t] = gates[rt * 64 + t];
  f32x4 acc[2][4] = {};
  for (int k0 = 0; k0 < 256; k0 += 64) {
    __syncthreads();
    {
      int r0 = sr, r1 = sr + 32, r2 = sr + 64, r3 = sr + 96;
      *(u16x8*)&As[r0 * 64 + ((sc ^ (r0 & 7)) * 8)] = pA0;
      *(u16x8*)&As[r1 * 64 + ((sc ^ (r1 & 7)) * 8)] = pA1;
      *(u16x8*)&Bs[r0 * 64 + ((sc ^ (r0 & 7)) * 8)] = pB0;
      *(u16x8*)&Bs[r1 * 64 + ((sc ^ (r1 & 7)) * 8)] = pB1;
      *(u16x8*)&Bs[r2 * 64 + ((sc ^ (r2 & 7)) * 8)] = pB2;
      *(u16x8*)&Bs[r3 * 64 + ((sc ^ (r3 & 7)) * 8)] = pB3;
    }
    __syncthreads();
    if (k0 < 192) {
      int off = k0 + 64;
      pA0 = *(const u16x8*)(aptr + off);
      pA1 = *(const u16x8*)(aptr + 32 * 256 + off);
      pB0 = *(const u16x8*)(bptr + off);
      pB1 = *(const u16x8*)(bptr + 32 * 256 + off);
      pB2 = *(const u16x8*)(bptr + 64 * 256 + off);
      pB3 = *(const u16x8*)(bptr + 96 * 256 + off);
    }
    #pragma unroll
    for (int kk = 0; kk < 2; kk++) {
      int ck = kk * 4 + (lane >> 4);
      bf16x8 a[2], b[4];
      #pragma unroll
      for (int mf = 0; mf < 2; mf++) {
        int ar = wm * 32 + mf * 16 + (lane & 15);
        a[mf] = as_bf16(*(const u16x8*)&As[ar * 64 + ((ck ^ (ar & 7)) * 8)]);
      }
      #pragma unroll
      for (int nf = 0; nf < 4; nf++) {
        int br = wn * 64 + nf * 16 + (lane & 15);
        b[nf] = as_bf16(*(const u16x8*)&Bs[br * 64 + ((ck ^ (br & 7)) * 8)]);
      }
      #pragma unroll
      for (int mf = 0; mf < 2; mf++)
        #pragma unroll
        for (int nf = 0; nf < 4; nf++)
          acc[mf][nf] = __builtin_amdgcn_mfma_f32_16x16x32_bf16(a[mf], b[nf], acc[mf][nf], 0, 0, 0);
    }
  }
  #pragma unroll
  for (int c = 0; c < 2; c++) {
    __syncthreads();
    if (wm == c) {
      #pragma unroll
      for (int mf = 0; mf < 2; mf++) {
        #pragma unroll
        for (int nf = 0; nf < 4; nf++) {
          int col = wn * 64 + nf * 16 + (lane & 15);
          #pragma unroll
          for (int j = 0; j < 4; j++) {
            int r = mf * 16 + (lane >> 4) * 4 + j;
            u.stage[r * 132 + col] = acc[mf][nf][j];
          }
        }
      }
    }
    if (c == 0) {
      #pragma unroll
      for (int i = 0; i < 4; i++)
        pref[1][i] = *(const f32x4*)(pbase + (size_t)(32 + i * 8) * 2048);
    }
    __syncthreads();
    #pragma unroll
    for (int i = 0; i < 4; i++) {
      int idx = i * 256 + t, r = idx >> 5, c4 = idx & 31;
      int row = rt * 64 + c * 32 + r;
      size_t o = (size_t)row * 2048 + ct * 128 + c4 * 4;
      f32x4 p = pref[c][i];
      f32x4 s = *(const f32x4*)&u.stage[r * 132 + c4 * 4];
      float g = gate_s[c * 32 + r];
      f32x4 ov;
      #pragma unroll
      for (int j = 0; j < 4; j++) ov[j] = p[j] + g * s[j];
      *(f32x4*)(out + o) = ov;
    }
  }
}

// ============================ launch ============================
extern "C" void kernel_launch(void* const* d_in, const int* in_sizes, int n_in,
                              void* d_out, int out_size, void* d_ws, size_t ws_size,
                              hipStream_t stream) {
  const float* hs      = (const float*)d_in[0];
  const float* primary = (const float*)d_in[1];
  const float* qw      = (const float*)d_in[2];
  const float* sk      = (const float*)d_in[3];
  const float* sv      = (const float*)d_in[4];
  const float* rel     = (const float*)d_in[5];
  const float* vdw     = (const float*)d_in[6];
  const float* vup     = (const float*)d_in[7];
  unsigned char* ws = (unsigned char*)d_ws;
  float* out = (float*)d_out;

  k_prep<<<dim3(256), dim3(256), 0, stream>>>(qw, sk, sv, vdw, vup, rel, ws);
  k_pv<<<dim3(256), dim3(256), 0, stream>>>(ws);
  k_query<<<dim3(512), dim3(256), 0, stream>>>(hs, ws);
  k_score<<<dim3(512), dim3(256), 0, stream>>>(ws);
  if (ws_size >= WS_NEED_SPLIT) {
    k_aux<<<dim3(2048), dim3(256), 0, stream>>>(ws);
    k_add<<<dim3(2048), dim3(256), 0, stream>>>(
        primary, (const unsigned short*)(ws + WS_AUX), out);
  } else {
    k_out<<<dim3(2048), dim3(256), 0, stream>>>(primary, out, ws);
  }
}

// Round 17
// 81.755 us; speedup vs baseline: 1.3317x; 1.3317x over previous
//
#include <hip/hip_runtime.h>
#include <stdint.h>

// ============================ problem dims ============================
// hidden_states [4,2048,2048] f32, rows R=8192, H=2048, BD=N=VBD=256, top-8
// out = primary + sigmoid(top1) * gelu_lowrank(softmax_top8 @ gathered vals)
// Key restructure: down-proj linear -> PV = slot_values @ Wd^T precomputed.
// R16 finding: pure streaming (k_add) measures 2.8 TB/s HBM / 3.8 effective
// -> fused k_out (2.4 TB/s) is ~85% of the practical RMW stream rate; the
// 46us plateau is bandwidth-structural, not schedule-limited.
// R17: revert to R13-best fused config + qp partials in BF16 (-16 MB traffic).

typedef float f32x4 __attribute__((ext_vector_type(4)));
typedef unsigned short u16x8 __attribute__((ext_vector_type(8)));
typedef unsigned short u16x4 __attribute__((ext_vector_type(4)));
typedef __bf16 bf16x8 __attribute__((ext_vector_type(8)));

// ============================ ws layout (bytes) ============================
#define WS_QW    0u          // u16 [256*2048]  q_proj_w bf16
#define WS_SK    1048576u    // u16 [256*256]   slot_keys bf16
#define WS_SV    1179648u    // u16 [256*2048]  slot_values bf16
#define WS_VDW   2228224u    // u16 [256*2048]  value_down_w bf16
#define WS_VUP   3276800u    // u16 [2048*256]  value_up_w bf16
#define WS_REL   4325376u    // f32 [256]       log(reliability)
#define WS_PV    4326400u    // f32 [256*256]   slot_values @ Wd^T
#define WS_GATE  4588544u    // f32 [8192]      sigmoid(top1)
#define WS_QP    4621312u    // u16 [2][8192][256] query split-K partials (bf16)
#define WS_D     21398528u   // u16 [8192*256]  gelu(down) bf16
// total ~24.4 MB

static __device__ __forceinline__ unsigned short f2bf(float f) {
  union { float f; unsigned int u; } v; v.f = f;
  unsigned int r = v.u + 0x7FFFu + ((v.u >> 16) & 1u);
  return (unsigned short)(r >> 16);
}
static __device__ __forceinline__ float bf2f(unsigned short b) {
  union { unsigned int u; float f; } v; v.u = ((unsigned int)b) << 16;
  return v.f;
}
static __device__ __forceinline__ bf16x8 as_bf16(u16x8 v) {
  return __builtin_bit_cast(bf16x8, v);
}
static __device__ __forceinline__ float gelu_tanh(float x) {
  float u = 0.7978845608028654f * (x + 0.044715f * x * x * x);
  return 0.5f * x * (1.0f + tanhf(u));
}

// ============================ K0: convert weights ============================
__global__ void k_prep(const float* __restrict__ qw, const float* __restrict__ sk,
                       const float* __restrict__ sv, const float* __restrict__ vdw,
                       const float* __restrict__ vup, const float* __restrict__ rel,
                       unsigned char* __restrict__ ws) {
  unsigned short* o_qw  = (unsigned short*)(ws + WS_QW);
  unsigned short* o_sk  = (unsigned short*)(ws + WS_SK);
  unsigned short* o_sv  = (unsigned short*)(ws + WS_SV);
  unsigned short* o_vdw = (unsigned short*)(ws + WS_VDW);
  unsigned short* o_vup = (unsigned short*)(ws + WS_VUP);
  float* o_rel = (float*)(ws + WS_REL);
  int tid = blockIdx.x * blockDim.x + threadIdx.x;
  int stride = gridDim.x * blockDim.x;
  for (int g = tid; g < 540736; g += stride) {
    const float* src; unsigned short* dst; int i;
    if      (g < 131072) { src = qw;  dst = o_qw;  i = g; }
    else if (g < 147456) { src = sk;  dst = o_sk;  i = g - 131072; }
    else if (g < 278528) { src = sv;  dst = o_sv;  i = g - 147456; }
    else if (g < 409600) { src = vdw; dst = o_vdw; i = g - 278528; }
    else if (g < 540672) { src = vup; dst = o_vup; i = g - 409600; }
    else {
      int i4 = (g - 540672) * 4;
      #pragma unroll
      for (int j = 0; j < 4; j++) o_rel[i4 + j] = logf(fmaxf(rel[i4 + j], 1e-10f));
      continue;
    }
    f32x4 v = *(const f32x4*)(src + (size_t)i * 4);
    u16x4 o;
    #pragma unroll
    for (int j = 0; j < 4; j++) o[j] = f2bf(v[j]);
    *(u16x4*)(dst + (size_t)i * 4) = o;
  }
}

// ============================ K_PV: PV = sv @ vdw^T (barrier-free K) ============================
__global__ __launch_bounds__(256, 4) void k_pv(unsigned char* __restrict__ ws) {
  const unsigned short* sv  = (const unsigned short*)(ws + WS_SV);
  const unsigned short* vdw = (const unsigned short*)(ws + WS_VDW);
  float* PV = (float*)(ws + WS_PV);
  __shared__ float red[4][16][16];
  int t = threadIdx.x, lane = t & 63, w = t >> 6;
  int nt = blockIdx.x >> 4, vt = blockIdx.x & 15;
  const unsigned short* aLane = sv  + (size_t)(nt * 16 + (lane & 15)) * 2048 + (lane >> 4) * 8 + w * 512;
  const unsigned short* bLane = vdw + (size_t)(vt * 16 + (lane & 15)) * 2048 + (lane >> 4) * 8 + w * 512;
  f32x4 acc = {0.f, 0.f, 0.f, 0.f};
  #pragma unroll
  for (int kt = 0; kt < 16; kt++) {
    bf16x8 a = as_bf16(*(const u16x8*)(aLane + kt * 32));
    bf16x8 b = as_bf16(*(const u16x8*)(bLane + kt * 32));
    acc = __builtin_amdgcn_mfma_f32_16x16x32_bf16(a, b, acc, 0, 0, 0);
  }
  int col = lane & 15, row0 = (lane >> 4) * 4;
  #pragma unroll
  for (int j = 0; j < 4; j++) red[w][row0 + j][col] = acc[j];
  __syncthreads();
  if (w == 0) {
    #pragma unroll
    for (int i = 0; i < 4; i++) {
      int idx = i * 64 + lane, r = idx >> 4, c = idx & 15;
      float s = red[0][r][c] + red[1][r][c] + red[2][r][c] + red[3][r][c];
      PV[(nt * 16 + r) * 256 + vt * 16 + c] = s;
    }
  }
}

// ============================ K1: query GEMM (split-K=2, pipelined, bf16 partials) ============================
__global__ __launch_bounds__(256, 4) void k_query(const float* __restrict__ hs,
                                                  unsigned char* __restrict__ ws) {
  const unsigned short* qw = (const unsigned short*)(ws + WS_QW);
  __shared__ __align__(16) unsigned short As[32 * 64];    // 4 KB
  __shared__ __align__(16) unsigned short Bs[256 * 64];   // 32 KB
  int t = threadIdx.x, lane = t & 63, w = t >> 6;
  int rt = blockIdx.x >> 1, ks = blockIdx.x & 1;
  int row0 = rt * 32, kbase = ks * 1024;
  f32x4 acc[2][4] = {};
  int sr = t >> 3, sc = t & 7;
  const float* aptr = hs + (size_t)(row0 + sr) * 2048 + kbase + sc * 8;
  const unsigned short* bptr = qw + (size_t)sr * 2048 + kbase + sc * 8;
  f32x4 pa0, pa1;
  u16x8 pb0, pb1, pb2, pb3, pb4, pb5, pb6, pb7;
  pa0 = *(const f32x4*)(aptr);
  pa1 = *(const f32x4*)(aptr + 4);
  pb0 = *(const u16x8*)(bptr + (size_t)0 * 32 * 2048);
  pb1 = *(const u16x8*)(bptr + (size_t)1 * 32 * 2048);
  pb2 = *(const u16x8*)(bptr + (size_t)2 * 32 * 2048);
  pb3 = *(const u16x8*)(bptr + (size_t)3 * 32 * 2048);
  pb4 = *(const u16x8*)(bptr + (size_t)4 * 32 * 2048);
  pb5 = *(const u16x8*)(bptr + (size_t)5 * 32 * 2048);
  pb6 = *(const u16x8*)(bptr + (size_t)6 * 32 * 2048);
  pb7 = *(const u16x8*)(bptr + (size_t)7 * 32 * 2048);
  for (int kt = 0; kt < 16; kt++) {
    __syncthreads();
    {
      u16x8 o;
      #pragma unroll
      for (int j = 0; j < 4; j++) { o[j] = f2bf(pa0[j]); o[4 + j] = f2bf(pa1[j]); }
      *(u16x8*)&As[sr * 64 + ((sc ^ (sr & 7)) * 8)] = o;
      u16x8 pb[8] = {pb0, pb1, pb2, pb3, pb4, pb5, pb6, pb7};
      #pragma unroll
      for (int i = 0; i < 8; i++) {
        int n = i * 32 + sr;
        *(u16x8*)&Bs[n * 64 + ((sc ^ (n & 7)) * 8)] = pb[i];
      }
    }
    __syncthreads();
    if (kt < 15) {
      int off = (kt + 1) * 64;
      pa0 = *(const f32x4*)(aptr + off);
      pa1 = *(const f32x4*)(aptr + off + 4);
      pb0 = *(const u16x8*)(bptr + (size_t)0 * 32 * 2048 + off);
      pb1 = *(const u16x8*)(bptr + (size_t)1 * 32 * 2048 + off);
      pb2 = *(const u16x8*)(bptr + (size_t)2 * 32 * 2048 + off);
      pb3 = *(const u16x8*)(bptr + (size_t)3 * 32 * 2048 + off);
      pb4 = *(const u16x8*)(bptr + (size_t)4 * 32 * 2048 + off);
      pb5 = *(const u16x8*)(bptr + (size_t)5 * 32 * 2048 + off);
      pb6 = *(const u16x8*)(bptr + (size_t)6 * 32 * 2048 + off);
      pb7 = *(const u16x8*)(bptr + (size_t)7 * 32 * 2048 + off);
    }
    #pragma unroll
    for (int kk = 0; kk < 2; kk++) {
      int ck = kk * 4 + (lane >> 4);
      bf16x8 a[2], b[4];
      #pragma unroll
      for (int mf = 0; mf < 2; mf++) {
        int arow = mf * 16 + (lane & 15);
        a[mf] = as_bf16(*(const u16x8*)&As[arow * 64 + ((ck ^ (arow & 7)) * 8)]);
      }
      #pragma unroll
      for (int nf = 0; nf < 4; nf++) {
        int brow = w * 64 + nf * 16 + (lane & 15);
        b[nf] = as_bf16(*(const u16x8*)&Bs[brow * 64 + ((ck ^ (brow & 7)) * 8)]);
      }
      #pragma unroll
      for (int mf = 0; mf < 2; mf++)
        #pragma unroll
        for (int nf = 0; nf < 4; nf++)
          acc[mf][nf] = __builtin_amdgcn_mfma_f32_16x16x32_bf16(a[mf], b[nf], acc[mf][nf], 0, 0, 0);
    }
  }
  unsigned short* outp = (unsigned short*)(ws + WS_QP) + (size_t)ks * 8192 * 256;
  #pragma unroll
  for (int mf = 0; mf < 2; mf++) {
    int row = row0 + mf * 16 + (lane >> 4) * 4;
    #pragma unroll
    for (int nf = 0; nf < 4; nf++) {
      int col = w * 64 + nf * 16 + (lane & 15);
      #pragma unroll
      for (int j = 0; j < 4; j++) outp[(size_t)(row + j) * 256 + col] = f2bf(acc[mf][nf][j]);
    }
  }
}

// ============================ K2: scores + wave-parallel top8 + PV gather ============================
#define QSTR 264   // ushort stride
#define SSTR 260   // f32 stride
__global__ __launch_bounds__(256, 4) void k_score(unsigned char* __restrict__ ws) {
  const unsigned short* qp = (const unsigned short*)(ws + WS_QP);
  const unsigned short* sk = (const unsigned short*)(ws + WS_SK);
  const float* relm = (const float*)(ws + WS_REL);
  const float* PV = (const float*)(ws + WS_PV);
  float* gates = (float*)(ws + WS_GATE);
  unsigned short* D = (unsigned short*)(ws + WS_D);
  __shared__ __align__(16) unsigned short Qs[16 * QSTR];
  __shared__ __align__(16) float Ss[16 * SSTR];
  int t = threadIdx.x, lane = t & 63, w = t >> 6;
  int row0 = blockIdx.x * 16;
  // phase 1: query = bf16(qp0) + bf16(qp1) -> bf16 -> Qs (16 rows x 256 cols)
  #pragma unroll
  for (int i = 0; i < 2; i++) {
    int id = i * 256 + t, r = id >> 5, c8 = id & 31;
    const unsigned short* p0 = qp + (size_t)(row0 + r) * 256 + c8 * 8;
    u16x8 a = *(const u16x8*)p0;
    u16x8 b = *(const u16x8*)(p0 + (size_t)8192 * 256);
    u16x8 o;
    #pragma unroll
    for (int j = 0; j < 8; j++) o[j] = f2bf(bf2f(a[j]) + bf2f(b[j]));
    *(u16x8*)&Qs[r * QSTR + c8 * 8] = o;
  }
  __syncthreads();
  // phase 2: scores[16][256] = Q @ sk^T / 16 + rel_mask
  {
    f32x4 acc[4] = {};
    for (int ksb = 0; ksb < 8; ksb++) {
      int ck = lane >> 4;
      bf16x8 a = as_bf16(*(const u16x8*)&Qs[(lane & 15) * QSTR + ksb * 32 + ck * 8]);
      #pragma unroll
      for (int nf = 0; nf < 4; nf++) {
        int n = w * 64 + nf * 16 + (lane & 15);
        bf16x8 b = as_bf16(*(const u16x8*)&sk[(size_t)n * 256 + ksb * 32 + ck * 8]);
        acc[nf] = __builtin_amdgcn_mfma_f32_16x16x32_bf16(a, b, acc[nf], 0, 0, 0);
      }
    }
    #pragma unroll
    for (int nf = 0; nf < 4; nf++) {
      int n = w * 64 + nf * 16 + (lane & 15);
      float rm = relm[n];
      int rr = (lane >> 4) * 4;
      #pragma unroll
      for (int j = 0; j < 4; j++) Ss[(rr + j) * SSTR + n] = acc[nf][j] * 0.0625f + rm;
    }
  }
  __syncthreads();
  // phase 3: wave w handles rows w*4 .. w*4+3
  for (int rr = 0; rr < 4; rr++) {
    int row = w * 4 + rr;
    f32x4 sv4 = *(const f32x4*)&Ss[row * SSTR + lane * 4];
    unsigned int key[4];
    #pragma unroll
    for (int j = 0; j < 4; j++) {
      unsigned int u = __builtin_bit_cast(unsigned int, sv4[j]);
      unsigned int os = (u & 0x80000000u) ? ~u : (u | 0x80000000u);
      key[j] = (os & 0xFFFFFF00u) | (unsigned int)(255 - (lane * 4 + j));
    }
    unsigned int win[8];
    #pragma unroll
    for (int e = 0; e < 8; e++) {
      unsigned int m01 = key[0] > key[1] ? key[0] : key[1];
      unsigned int m23 = key[2] > key[3] ? key[2] : key[3];
      unsigned int m = m01 > m23 ? m01 : m23;
      #pragma unroll
      for (int d = 1; d < 64; d <<= 1) {
        unsigned int o = (unsigned int)__shfl_xor((int)m, d, 64);
        m = o > m ? o : m;
      }
      win[e] = m;
      #pragma unroll
      for (int j = 0; j < 4; j++) if (key[j] == m) key[j] = 0u;
    }
    float s8[8]; int i8[8];
    #pragma unroll
    for (int e = 0; e < 8; e++) {
      i8[e] = 255 - (int)(win[e] & 0xFFu);
      unsigned int os = win[e] & 0xFFFFFF00u;
      unsigned int u = (os & 0x80000000u) ? (os ^ 0x80000000u) : ~os;
      s8[e] = __builtin_bit_cast(float, u);
    }
    float m0 = s8[0], sum = 0.f, we[8];
    #pragma unroll
    for (int e = 0; e < 8; e++) { we[e] = expf(s8[e] - m0); sum += we[e]; }
    float inv = 1.f / sum;
    f32x4 accv = {0.f, 0.f, 0.f, 0.f};
    #pragma unroll
    for (int e = 0; e < 8; e++) {
      float wk = we[e] * inv;
      f32x4 p = *(const f32x4*)(PV + (size_t)i8[e] * 256 + lane * 4);
      #pragma unroll
      for (int j = 0; j < 4; j++) accv[j] += wk * p[j];
    }
    u16x4 o;
    #pragma unroll
    for (int j = 0; j < 4; j++) o[j] = f2bf(gelu_tanh(accv[j]));
    *(u16x4*)&D[(size_t)(row0 + row) * 256 + lane * 4] = o;
    if (lane == 0) gates[row0 + row] = 1.f / (1.f + expf(-m0));
  }
}

// ============================ K3: up-GEMM + epilogue (R13 best: 46.2us) ============================
// Tripwires: VGPR_Count ~64, WRITE_SIZE == 65536 KB.
union KOutLds {
  unsigned short AB[12288];        // As 64x64 at [0], Bs 128x64 at +4096
  float stage[32 * 132];
};
__global__ __launch_bounds__(256, 4) void k_out(const float* __restrict__ primary,
                                                float* __restrict__ out,
                                                unsigned char* __restrict__ ws) {
  const unsigned short* D = (const unsigned short*)(ws + WS_D);
  const unsigned short* vup = (const unsigned short*)(ws + WS_VUP);
  const float* gates = (const float*)(ws + WS_GATE);
  __shared__ __align__(16) KOutLds u;
  __shared__ float gate_s[64];
  unsigned short* As = u.AB;
  unsigned short* Bs = u.AB + 4096;
  int t = threadIdx.x, lane = t & 63, w = t >> 6;
  int bid = blockIdx.x;
  int L = (bid & 7) * 256 + (bid >> 3);   // bijective: 2048 % 8 == 0
  int rt = L >> 4, ct = L & 15;
  int wm = w >> 1, wn = w & 1;
  const float* pbase = primary + (size_t)(rt * 64 + (t >> 5)) * 2048 + ct * 128 + (t & 31) * 4;
  f32x4 pref[2][4];
  #pragma unroll
  for (int i = 0; i < 4; i++)
    pref[0][i] = *(const f32x4*)(pbase + (size_t)(i * 8) * 2048);
  int sr = t >> 3, sc = t & 7;
  const unsigned short* aptr = D + (size_t)(rt * 64 + sr) * 256 + sc * 8;
  const unsigned short* bptr = vup + (size_t)(ct * 128 + sr) * 256 + sc * 8;
  u16x8 pA0, pA1, pB0, pB1, pB2, pB3;
  pA0 = *(const u16x8*)(aptr);
  pA1 = *(const u16x8*)(aptr + 32 * 256);
  pB0 = *(const u16x8*)(bptr);
  pB1 = *(const u16x8*)(bptr + 32 * 256);
  pB2 = *(const u16x8*)(bptr + 64 * 256);
  pB3 = *(const u16x8*)(bptr + 96 * 256);
  if (t < 64) gate_s[t] = gates[rt * 64 + t];
  f32x4 acc[2][4] = {};
  for (int k0 = 0; k0 < 256; k0 += 64) {
    __syncthreads();
    {
      int r0 = sr, r1 = sr + 32, r2 = sr + 64, r3 = sr + 96;
      *(u16x8*)&As[r0 * 64 + ((sc ^ (r0 & 7)) * 8)] = pA0;
      *(u16x8*)&As[r1 * 64 + ((sc ^ (r1 & 7)) * 8)] = pA1;
      *(u16x8*)&Bs[r0 * 64 + ((sc ^ (r0 & 7)) * 8)] = pB0;
      *(u16x8*)&Bs[r1 * 64 + ((sc ^ (r1 & 7)) * 8)] = pB1;
      *(u16x8*)&Bs[r2 * 64 + ((sc ^ (r2 & 7)) * 8)] = pB2;
      *(u16x8*)&Bs[r3 * 64 + ((sc ^ (r3 & 7)) * 8)] = pB3;
    }
    __syncthreads();
    if (k0 < 192) {
      int off = k0 + 64;
      pA0 = *(const u16x8*)(aptr + off);
      pA1 = *(const u16x8*)(aptr + 32 * 256 + off);
      pB0 = *(const u16x8*)(bptr + off);
      pB1 = *(const u16x8*)(bptr + 32 * 256 + off);
      pB2 = *(const u16x8*)(bptr + 64 * 256 + off);
      pB3 = *(const u16x8*)(bptr + 96 * 256 + off);
    }
    #pragma unroll
    for (int kk = 0; kk < 2; kk++) {
      int ck = kk * 4 + (lane >> 4);
      bf16x8 a[2], b[4];
      #pragma unroll
      for (int mf = 0; mf < 2; mf++) {
        int ar = wm * 32 + mf * 16 + (lane & 15);
        a[mf] = as_bf16(*(const u16x8*)&As[ar * 64 + ((ck ^ (ar & 7)) * 8)]);
      }
      #pragma unroll
      for (int nf = 0; nf < 4; nf++) {
        int br = wn * 64 + nf * 16 + (lane & 15);
        b[nf] = as_bf16(*(const u16x8*)&Bs[br * 64 + ((ck ^ (br & 7)) * 8)]);
      }
      #pragma unroll
      for (int mf = 0; mf < 2; mf++)
        #pragma unroll
        for (int nf = 0; nf < 4; nf++)
          acc[mf][nf] = __builtin_amdgcn_mfma_f32_16x16x32_bf16(a[mf], b[nf], acc[mf][nf], 0, 0, 0);
    }
  }
  #pragma unroll
  for (int c = 0; c < 2; c++) {
    __syncthreads();
    if (wm == c) {
      #pragma unroll
      for (int mf = 0; mf < 2; mf++) {
        #pragma unroll
        for (int nf = 0; nf < 4; nf++) {
          int col = wn * 64 + nf * 16 + (lane & 15);
          #pragma unroll
          for (int j = 0; j < 4; j++) {
            int r = mf * 16 + (lane >> 4) * 4 + j;
            u.stage[r * 132 + col] = acc[mf][nf][j];
          }
        }
      }
    }
    if (c == 0) {
      #pragma unroll
      for (int i = 0; i < 4; i++)
        pref[1][i] = *(const f32x4*)(pbase + (size_t)(32 + i * 8) * 2048);
    }
    __syncthreads();
    #pragma unroll
    for (int i = 0; i < 4; i++) {
      int idx = i * 256 + t, r = idx >> 5, c4 = idx & 31;
      int row = rt * 64 + c * 32 + r;
      size_t o = (size_t)row * 2048 + ct * 128 + c4 * 4;
      f32x4 p = pref[c][i];
      f32x4 s = *(const f32x4*)&u.stage[r * 132 + c4 * 4];
      float g = gate_s[c * 32 + r];
      f32x4 ov;
      #pragma unroll
      for (int j = 0; j < 4; j++) ov[j] = p[j] + g * s[j];
      *(f32x4*)(out + o) = ov;
    }
  }
}

// ============================ launch ============================
extern "C" void kernel_launch(void* const* d_in, const int* in_sizes, int n_in,
                              void* d_out, int out_size, void* d_ws, size_t ws_size,
                              hipStream_t stream) {
  const float* hs      = (const float*)d_in[0];
  const float* primary = (const float*)d_in[1];
  const float* qw      = (const float*)d_in[2];
  const float* sk      = (const float*)d_in[3];
  const float* sv      = (const float*)d_in[4];
  const float* rel     = (const float*)d_in[5];
  const float* vdw     = (const float*)d_in[6];
  const float* vup     = (const float*)d_in[7];
  unsigned char* ws = (unsigned char*)d_ws;
  float* out = (float*)d_out;

  k_prep<<<dim3(256), dim3(256), 0, stream>>>(qw, sk, sv, vdw, vup, rel, ws);
  k_pv<<<dim3(256), dim3(256), 0, stream>>>(ws);
  k_query<<<dim3(512), dim3(256), 0, stream>>>(hs, ws);
  k_score<<<dim3(512), dim3(256), 0, stream>>>(ws);
  k_out<<<dim3(2048), dim3(256), 0, stream>>>(primary, out, ws);
}